// Round 1
// 475.201 us; speedup vs baseline: 1.0547x; 1.0547x over previous
//
#include <hip/hip_runtime.h>

// Problem constants
#define N_TOK 8192
#define DIM   4096
#define NEXP  8
#define RANK  128
#define EK    (NEXP * RANK)   // 1024 = flattened (expert, rank) K dim for GEMM2
#define SCAL  0.25f           // LORA_ALPHA / R = 32/128

typedef unsigned short u16;
typedef __bf16 bf16x8 __attribute__((ext_vector_type(8)));
typedef float  f32x4  __attribute__((ext_vector_type(4)));

typedef const __attribute__((address_space(1))) void* as1_cvp;
typedef __attribute__((address_space(3))) void*       as3_vp;

__device__ __forceinline__ void async16(void* lds, const void* g) {
  // 16B-per-lane direct global->LDS (global_load_lds_dwordx4). LDS dest must be
  // wave-uniform base + lane*16 — all call sites arrange lds = base + tid*16B.
  __builtin_amdgcn_global_load_lds((as1_cvp)g, (as3_vp)lds, 16, 0, 0);
}

__device__ __forceinline__ u16 f2bf(float f) {  // RNE float->bf16 bits
  unsigned int u = __builtin_bit_cast(unsigned int, f);
  u += 0x7fffu + ((u >> 16) & 1u);
  return (u16)(u >> 16);
}

__device__ __forceinline__ f32x4 mfma16(bf16x8 a, bf16x8 b, f32x4 c) {
  return __builtin_amdgcn_mfma_f32_16x16x32_bf16(a, b, c, 0, 0, 0);
}

// Counted-vmcnt pipeline fences (gemm2). Raw s_barrier — __syncthreads would
// emit s_waitcnt vmcnt(0) and drain the prefetch queue (the m97 ~20% stall).
// sched_barrier(0) pins compiler scheduling at the fence (rule #18 analog).
#define PIPE_WAIT(N)                                            \
  __builtin_amdgcn_sched_barrier(0);                            \
  asm volatile("s_waitcnt vmcnt(" #N ")" ::: "memory");         \
  __builtin_amdgcn_s_barrier();                                 \
  __builtin_amdgcn_sched_barrier(0)

#define PIPE_END()                                              \
  __builtin_amdgcn_sched_barrier(0);                            \
  __builtin_amdgcn_s_barrier();                                 \
  __builtin_amdgcn_sched_barrier(0)

// ---------------------------------------------------------------- converts
__global__ __launch_bounds__(256) void cvtA_kernel(const float* __restrict__ A,
                                                   u16* __restrict__ Ab) {
  size_t i = (size_t)blockIdx.x * 256 + threadIdx.x;  // float4 index, same layout
  float4 v = ((const float4*)A)[i];
  ushort4 o;
  o.x = f2bf(v.x); o.y = f2bf(v.y); o.z = f2bf(v.z); o.w = f2bf(v.w);
  ((ushort4*)Ab)[i] = o;
}

// B[e][o][r] fp32 -> Bt[o][e*128+r] bf16 (BT layout for GEMM2, k-contiguous rows)
__global__ __launch_bounds__(256) void cvtB_kernel(const float* __restrict__ B,
                                                   u16* __restrict__ Bt) {
  size_t i = (size_t)blockIdx.x * 256 + threadIdx.x;  // enumerates (e, o, r/4)
  int r4 = (int)(i & 31);
  int o_ = (int)((i >> 5) & 4095);
  int e  = (int)(i >> 17);
  float4 v = ((const float4*)B)[i];
  ushort4 u;
  u.x = f2bf(v.x); u.y = f2bf(v.y); u.z = f2bf(v.z); u.w = f2bf(v.w);
  ((ushort4*)Bt)[(size_t)o_ * 256 + e * 32 + r4] = u;
}

// ---------------------------------------------------------------- router
// fp32 router (bf16 would flip near-tie expert picks), fused x->bf16 convert.
__device__ __forceinline__ void router_finalize(
    int n, const float* l_in, const float* __restrict__ br,
    float* __restrict__ gw, int* __restrict__ sel) {
  float l[NEXP];
#pragma unroll
  for (int e = 0; e < NEXP; ++e) l[e] = l_in[e] + br[e];
  int i0 = 0;
#pragma unroll
  for (int e = 1; e < NEXP; ++e) if (l[e] > l[i0]) i0 = e;
  int i1 = (i0 == 0) ? 1 : 0;
#pragma unroll
  for (int e = 0; e < NEXP; ++e) if (e != i0 && l[e] > l[i1]) i1 = e;
  // renormalized top-2 gate: w0 = exp(l0)/(exp(l0)+exp(l1)); l1<=l0 so no ovf
  float w0 = 1.f / (1.f + expf(l[i1] - l[i0]));
  gw[n * 2 + 0] = w0 * SCAL;
  gw[n * 2 + 1] = (1.f - w0) * SCAL;
  sel[n] = i0 | (i1 << 4);
}

__global__ __launch_bounds__(256) void router_kernel(
    const float* __restrict__ x, const float* __restrict__ Wr,
    const float* __restrict__ br, u16* __restrict__ xb,
    float* __restrict__ gw, int* __restrict__ sel) {
  const int tid = threadIdx.x;
  const int wv = tid >> 6, lane = tid & 63;
  const int n0 = (blockIdx.x * 4 + wv) * 2;  // this wave's 2 tokens
  const float4* x4 = (const float4*)x;
  const float4* w4 = (const float4*)Wr;

  const float4* xr0 = x4 + (size_t)n0 * 1024;
  const float4* xr1 = x4 + (size_t)(n0 + 1) * 1024;
  ushort4* xo0 = (ushort4*)(xb + (size_t)n0 * DIM);
  ushort4* xo1 = (ushort4*)(xb + (size_t)(n0 + 1) * DIM);

  float s0[NEXP] = {}, s1[NEXP] = {};
#pragma unroll 4
  for (int it = 0; it < 16; ++it) {
    const int col = it * 64 + lane;  // float4 column index; lanes coalesced
    float4 xv0 = xr0[col];
    float4 xv1 = xr1[col];
    ushort4 o0, o1;
    o0.x = f2bf(xv0.x); o0.y = f2bf(xv0.y); o0.z = f2bf(xv0.z); o0.w = f2bf(xv0.w);
    o1.x = f2bf(xv1.x); o1.y = f2bf(xv1.y); o1.z = f2bf(xv1.z); o1.w = f2bf(xv1.w);
    xo0[col] = o0;
    xo1[col] = o1;
#pragma unroll
    for (int e = 0; e < NEXP; ++e) {
      float4 wv4 = w4[(size_t)e * 1024 + col];  // L2-resident (128 KB total)
      s0[e] += xv0.x * wv4.x + xv0.y * wv4.y + xv0.z * wv4.z + xv0.w * wv4.w;
      s1[e] += xv1.x * wv4.x + xv1.y * wv4.y + xv1.z * wv4.z + xv1.w * wv4.w;
    }
  }
  // one butterfly per wave (96 DS ops for 8192 loaded floats)
#pragma unroll
  for (int m = 1; m < 64; m <<= 1)
#pragma unroll
    for (int e = 0; e < NEXP; ++e) {
      s0[e] += __shfl_xor(s0[e], m, 64);
      s1[e] += __shfl_xor(s1[e], m, 64);
    }
  if (lane == 0)      router_finalize(n0,     s0, br, gw, sel);
  else if (lane == 1) router_finalize(n0 + 1, s1, br, gw, sel);
}

// ---------------------------------------------------------------- listbuild
// Ballot-aggregated expert-list compaction. 16 blocks x 512 thr, 1 token/thr.
__global__ __launch_bounds__(512) void listbuild_kernel(
    const int* __restrict__ sel, int* __restrict__ lists,
    int* __restrict__ cnt) {
  __shared__ int blkCnt[NEXP];
  __shared__ int gBase[NEXP];
  __shared__ int waveOff[8][NEXP];
  const int tid = threadIdx.x;
  const int wv = tid >> 6, lane = tid & 63;
  const int n = blockIdx.x * 512 + tid;
  if (tid < NEXP) blkCnt[tid] = 0;
  __syncthreads();
  const int s = sel[n];
  const int i0 = s & 15, i1 = (s >> 4) & 15;
#pragma unroll
  for (int e = 0; e < NEXP; ++e) {
    unsigned long long m0 = __ballot(i0 == e);
    unsigned long long m1 = __ballot(i1 == e);
    if (lane == 0)
      waveOff[wv][e] = atomicAdd(&blkCnt[e], __popcll(m0) + __popcll(m1));
  }
  __syncthreads();
  if (tid < NEXP) gBase[tid] = atomicAdd(&cnt[tid], blkCnt[tid]);
  __syncthreads();
  const unsigned long long lt = (1ull << lane) - 1;
#pragma unroll
  for (int e = 0; e < NEXP; ++e) {
    unsigned long long m0 = __ballot(i0 == e);
    unsigned long long m1 = __ballot(i1 == e);
    int base = gBase[e] + waveOff[wv][e];
    if (i0 == e) lists[e * N_TOK + base + (int)__popcll(m0 & lt)] = n * 2;
    if (i1 == e)
      lists[e * N_TOK + base + (int)__popcll(m0) + (int)__popcll(m1 & lt)] =
          n * 2 + 1;
  }
}

// ---------------------------------------------------------------- GEMM1
// Per expert: h[entry, r] = xb[token] . Ab[e][r], scaled by gate*SCAL -> G bf16.
// Tile: 64 entries x 128 (full R) x BK=64, 256 threads (4 waves, each 32x64).
__global__ __launch_bounds__(256) void gemm1_kernel(
    const u16* __restrict__ xb, const u16* __restrict__ Ab,
    const int* __restrict__ lists, const int* __restrict__ cnt,
    const float* __restrict__ gw, u16* __restrict__ G) {
  const int e = blockIdx.y;
  const int mt = blockIdx.x;
  const int c = cnt[e];
  if (mt * 64 >= c) return;

  __shared__ alignas(16) u16 As[64 * 64];
  __shared__ alignas(16) u16 Bs[128 * 64];
  __shared__ int   tokS[64];
  __shared__ float wS[64];

  const int tid = threadIdx.x;
  if (tid < 64) {
    int idx = mt * 64 + tid;
    int ci = idx < c ? idx : (c - 1);
    int entry = lists[e * N_TOK + ci];
    tokS[tid] = entry >> 1;
    wS[tid] = (idx < c) ? gw[entry] : 0.0f;
  }
  __syncthreads();

  const int lr = tid >> 3;  // 0..31 staging row
  const int cg = tid & 7;   // 16B column group
  const u16* ga0 = xb + (size_t)tokS[lr] * DIM + cg * 8;
  const u16* ga1 = xb + (size_t)tokS[lr + 32] * DIM + cg * 8;
  const u16* gb  = Ab + (size_t)e * (RANK * DIM) + (size_t)lr * DIM + cg * 8;

  const int lane = tid & 63, wvi = tid >> 6;
  const int wm = wvi >> 1, wn = wvi & 1;
  const int m16 = lane & 15, quad = lane >> 4;

  f32x4 acc[2][4] = {};

  for (int k0 = 0; k0 < DIM; k0 += 64) {
    async16(&As[tid * 8], ga0 + k0);
    async16(&As[tid * 8 + 2048], ga1 + k0);
#pragma unroll
    for (int r = 0; r < 4; ++r)
      async16(&Bs[tid * 8 + r * 2048], gb + (size_t)r * 32 * DIM + k0);
    __syncthreads();
#pragma unroll
    for (int ks = 0; ks < 2; ++ks) {
      const int ko = ks * 32 + quad * 8;
      bf16x8 af[2], bfr[4];
#pragma unroll
      for (int i = 0; i < 2; ++i)
        af[i] = *(const bf16x8*)&As[(wm * 32 + i * 16 + m16) * 64 + ko];
#pragma unroll
      for (int j = 0; j < 4; ++j)
        bfr[j] = *(const bf16x8*)&Bs[(wn * 64 + j * 16 + m16) * 64 + ko];
#pragma unroll
      for (int i = 0; i < 2; ++i)
#pragma unroll
        for (int j = 0; j < 4; ++j) acc[i][j] = mfma16(af[i], bfr[j], acc[i][j]);
    }
    __syncthreads();
  }

#pragma unroll
  for (int i = 0; i < 2; ++i)
#pragma unroll
    for (int rr = 0; rr < 4; ++rr) {
      int row = wm * 32 + i * 16 + quad * 4 + rr;  // C/D: row=quad*4+reg
      if (mt * 64 + row < c) {
        int tk = tokS[row];
        float wgt = wS[row];
        u16* gp = G + (size_t)tk * EK + e * RANK + wn * 64 + m16;  // col=lane&15
#pragma unroll
        for (int j = 0; j < 4; ++j) gp[j * 16] = f2bf(acc[i][j][rr] * wgt);
      }
    }
}

// ---------------------------------------------------------------- GEMM2
// Dense: out[8192,4096] = G[8192,1024] @ Bt[4096,1024]^T.
// 256x256 tile, BK=32, 512 thr (8 waves 2x4, each 128x64 of C).
// 4-slot LDS ring (128 KiB), prefetch depth 3, counted s_waitcnt vmcnt(8) —
// loads NEVER drain to 0 in the main loop (T3+T4). Raw s_barrier only.
// Race-freedom: tile kt lives in slot kt&3. STAGE(t+3) is issued after the
// PIPE_WAIT barrier of iter t, which is after the PIPE_END barrier of iter
// t-1, which follows ALL waves' reads of tile t-1 (same slot (t+3)&3). Reads
// of tile t are safe because every wave executed vmcnt(8) (own t-loads
// landed; only t+1..t+3's 8-12 loads outstanding) before that same barrier.
// LDS bank geometry: rows are 32 bf16 = 64 B, and a frag ds_read_b128 (16
// rows x 4 quads) covers a CONTIGUOUS 1 KiB block -> conflict-free (the old
// [*][64] layout had bank = f(ks,quad) independent of row = 16-way conflict,
// the measured 2.5e7 SQ_LDS_BANK_CONFLICT).
__global__ __launch_bounds__(512, 2) void gemm2_kernel(
    const u16* __restrict__ G, const u16* __restrict__ Bt,
    float* __restrict__ out) {
  __shared__ alignas(16) u16 ring[4][2][256 * 32];  // 4 x (A 16KB + B 16KB)

  // T1: bijective XCD swizzle (512 wgs, 512 % 8 == 0). XCD x gets a
  // contiguous band of 4 m-tiles (1024 G rows = 2 MB, L2-resident).
  const int lin = blockIdx.y * 16 + blockIdx.x;
  const int swz = (lin & 7) * 64 + (lin >> 3);
  const int by = swz >> 4;  // m-tile 0..31
  const int bx = swz & 15;  // n-tile 0..15

  const int tid = threadIdx.x;
  const int sr = tid >> 2;        // staging row 0..127 within half
  const int sc = (tid & 3) * 8;   // staging 16B col group
  const u16* gA = G  + (size_t)(by * 256 + sr) * EK + sc;
  const u16* gB = Bt + (size_t)(bx * 256 + sr) * EK + sc;

  const int lane = tid & 63, wvi = tid >> 6;  // 8 waves
  const int wm = wvi >> 2, wn = wvi & 3;      // 2 x 4 wave grid
  const int m16 = lane & 15, quad = lane >> 4;

  f32x4 acc[8][4] = {};

  auto STAGE = [&](int kt, int slot) {
    u16* lA = &ring[slot][0][tid * 8];   // linear dest = base + tid*16B
    u16* lB = &ring[slot][1][tid * 8];
    const u16* sA = gA + kt * 32;
    const u16* sB = gB + kt * 32;
    async16(lA,        sA);
    async16(lA + 4096, sA + (size_t)128 * EK);
    async16(lB,        sB);
    async16(lB + 4096, sB + (size_t)128 * EK);
  };

  auto COMPUTE = [&](int slot) {
    const u16* As_ = &ring[slot][0][0];
    const u16* Bs_ = &ring[slot][1][0];
    bf16x8 bfr[4];
#pragma unroll
    for (int j = 0; j < 4; ++j)
      bfr[j] = *(const bf16x8*)&Bs_[(wn * 64 + j * 16 + m16) * 32 + quad * 8];
    __builtin_amdgcn_s_setprio(1);  // T5: favor the MFMA cluster
#pragma unroll
    for (int i = 0; i < 8; ++i) {
      bf16x8 af = *(const bf16x8*)&As_[(wm * 128 + i * 16 + m16) * 32 + quad * 8];
#pragma unroll
      for (int j = 0; j < 4; ++j) acc[i][j] = mfma16(af, bfr[j], acc[i][j]);
    }
    __builtin_amdgcn_s_setprio(0);
  };

  // Prologue: fill 3 of 4 ring slots (12 loads in flight).
  STAGE(0, 0);
  STAGE(1, 1);
  STAGE(2, 2);

  // Main loop: 32 K-tiles (EK/32). vmcnt(8) = tiles t+1,t+2 stay in flight.
  for (int t = 0; t < 29; ++t) {
    PIPE_WAIT(8);
    STAGE(t + 3, (t + 3) & 3);  // overlapped with compute below
    COMPUTE(t & 3);
    PIPE_END();
  }
  PIPE_WAIT(8); COMPUTE(1); PIPE_END();  // t=29
  PIPE_WAIT(4); COMPUTE(2); PIPE_END();  // t=30
  PIPE_WAIT(0); COMPUTE(3); PIPE_END();  // t=31

#pragma unroll
  for (int i = 0; i < 8; ++i)
#pragma unroll
    for (int rr = 0; rr < 4; ++rr) {
      int row = by * 256 + wm * 128 + i * 16 + quad * 4 + rr;
      float* op = out + (size_t)row * DIM + bx * 256 + wn * 64 + m16;
#pragma unroll
      for (int j = 0; j < 4; ++j) op[j * 16] = acc[i][j][rr];
    }
}

// ---------------------------------------------------------------- launch
extern "C" void kernel_launch(void* const* d_in, const int* in_sizes, int n_in,
                              void* d_out, int out_size, void* d_ws, size_t ws_size,
                              hipStream_t stream) {
  const float* x  = (const float*)d_in[0];
  const float* Wr = (const float*)d_in[1];
  const float* br = (const float*)d_in[2];
  const float* A  = (const float*)d_in[3];
  const float* B  = (const float*)d_in[4];
  float* out = (float*)d_out;

  char* w = (char*)d_ws;
  u16* xb = (u16*)w;      w += (size_t)N_TOK * DIM * 2;        // 67.1 MB
  u16* G  = (u16*)w;      w += (size_t)N_TOK * EK * 2;         // 16.8 MB
  u16* Ab = (u16*)w;      w += (size_t)NEXP * RANK * DIM * 2;  //  8.4 MB
  u16* Bt = (u16*)w;      w += (size_t)DIM * EK * 2;           //  8.4 MB
  float* gw = (float*)w;  w += (size_t)N_TOK * 2 * 4;          // 64 KB
  int* lists = (int*)w;   w += (size_t)NEXP * N_TOK * 4;       // 256 KB
  int* sel = (int*)w;     w += (size_t)N_TOK * 4;              // 32 KB
  int* cnt = (int*)w;     w += 256;

  hipMemsetAsync(cnt, 0, NEXP * sizeof(int), stream);
  hipMemsetAsync(G, 0, (size_t)N_TOK * EK * 2, stream);  // unselected blocks = 0

  cvtA_kernel<<<dim3(4096), dim3(256), 0, stream>>>(A, Ab);
  cvtB_kernel<<<dim3(4096), dim3(256), 0, stream>>>(B, Bt);
  router_kernel<<<dim3(1024), dim3(256), 0, stream>>>(x, Wr, br, xb, gw, sel);
  listbuild_kernel<<<dim3(16), dim3(512), 0, stream>>>(sel, lists, cnt);
  gemm1_kernel<<<dim3(128, NEXP), dim3(256), 0, stream>>>(xb, Ab, lists, cnt, gw, G);
  gemm2_kernel<<<dim3(16, 32), dim3(512), 0, stream>>>(G, Bt, out);
}

// Round 2
// 446.656 us; speedup vs baseline: 1.1222x; 1.0639x over previous
//
#include <hip/hip_runtime.h>

// Problem constants
#define N_TOK 8192
#define DIM   4096
#define NEXP  8
#define RANK  128
#define EK    (NEXP * RANK)   // 1024 = flattened (expert, rank) K dim for GEMM2
#define SCAL  0.25f           // LORA_ALPHA / R = 32/128

typedef unsigned short u16;
typedef __bf16 bf16x8 __attribute__((ext_vector_type(8)));
typedef float  f32x4  __attribute__((ext_vector_type(4)));

typedef const __attribute__((address_space(1))) void* as1_cvp;
typedef __attribute__((address_space(3))) void*       as3_vp;

__device__ __forceinline__ void async16(void* lds, const void* g) {
  // 16B-per-lane direct global->LDS (global_load_lds_dwordx4). LDS dest must be
  // wave-uniform base + lane*16 — all call sites arrange lds = base + tid*16B.
  __builtin_amdgcn_global_load_lds((as1_cvp)g, (as3_vp)lds, 16, 0, 0);
}

__device__ __forceinline__ u16 f2bf(float f) {  // RNE float->bf16 bits
  unsigned int u = __builtin_bit_cast(unsigned int, f);
  u += 0x7fffu + ((u >> 16) & 1u);
  return (u16)(u >> 16);
}

__device__ __forceinline__ f32x4 mfma16(bf16x8 a, bf16x8 b, f32x4 c) {
  return __builtin_amdgcn_mfma_f32_16x16x32_bf16(a, b, c, 0, 0, 0);
}

// Counted-vmcnt pipeline fences. Raw s_barrier — __syncthreads would emit
// s_waitcnt vmcnt(0) and drain the prefetch queue (the m97 ~20% stall).
// sched_barrier(0) pins compiler scheduling at the fence (rule #18 analog).
#define PIPE_WAIT(N)                                            \
  __builtin_amdgcn_sched_barrier(0);                            \
  asm volatile("s_waitcnt vmcnt(" #N ")" ::: "memory");         \
  __builtin_amdgcn_s_barrier();                                 \
  __builtin_amdgcn_sched_barrier(0)

#define PIPE_END()                                              \
  __builtin_amdgcn_sched_barrier(0);                            \
  __builtin_amdgcn_s_barrier();                                 \
  __builtin_amdgcn_sched_barrier(0)

// ---------------------------------------------------------------- converts
__global__ __launch_bounds__(256) void cvtA_kernel(const float* __restrict__ A,
                                                   u16* __restrict__ Ab) {
  size_t i = (size_t)blockIdx.x * 256 + threadIdx.x;  // float4 index, same layout
  float4 v = ((const float4*)A)[i];
  ushort4 o;
  o.x = f2bf(v.x); o.y = f2bf(v.y); o.z = f2bf(v.z); o.w = f2bf(v.w);
  ((ushort4*)Ab)[i] = o;
}

// B[e][o][r] fp32 -> Bt[o][e*128+r] bf16 (BT layout for GEMM2, k-contiguous rows)
__global__ __launch_bounds__(256) void cvtB_kernel(const float* __restrict__ B,
                                                   u16* __restrict__ Bt) {
  size_t i = (size_t)blockIdx.x * 256 + threadIdx.x;  // enumerates (e, o, r/4)
  int r4 = (int)(i & 31);
  int o_ = (int)((i >> 5) & 4095);
  int e  = (int)(i >> 17);
  float4 v = ((const float4*)B)[i];
  ushort4 u;
  u.x = f2bf(v.x); u.y = f2bf(v.y); u.z = f2bf(v.z); u.w = f2bf(v.w);
  ((ushort4*)Bt)[(size_t)o_ * 256 + e * 32 + r4] = u;
}

// ---------------------------------------------------------------- router
// fp32 router (bf16 would flip near-tie expert picks), fused x->bf16 convert.
__device__ __forceinline__ void router_finalize(
    int n, const float* l_in, const float* __restrict__ br,
    float* __restrict__ gw, int* __restrict__ sel) {
  float l[NEXP];
#pragma unroll
  for (int e = 0; e < NEXP; ++e) l[e] = l_in[e] + br[e];
  int i0 = 0;
#pragma unroll
  for (int e = 1; e < NEXP; ++e) if (l[e] > l[i0]) i0 = e;
  int i1 = (i0 == 0) ? 1 : 0;
#pragma unroll
  for (int e = 0; e < NEXP; ++e) if (e != i0 && l[e] > l[i1]) i1 = e;
  // renormalized top-2 gate: w0 = exp(l0)/(exp(l0)+exp(l1)); l1<=l0 so no ovf
  float w0 = 1.f / (1.f + expf(l[i1] - l[i0]));
  gw[n * 2 + 0] = w0 * SCAL;
  gw[n * 2 + 1] = (1.f - w0) * SCAL;
  sel[n] = i0 | (i1 << 4);
}

__global__ __launch_bounds__(256) void router_kernel(
    const float* __restrict__ x, const float* __restrict__ Wr,
    const float* __restrict__ br, u16* __restrict__ xb,
    float* __restrict__ gw, int* __restrict__ sel) {
  const int tid = threadIdx.x;
  const int wv = tid >> 6, lane = tid & 63;
  const int n0 = (blockIdx.x * 4 + wv) * 2;  // this wave's 2 tokens
  const float4* x4 = (const float4*)x;
  const float4* w4 = (const float4*)Wr;

  const float4* xr0 = x4 + (size_t)n0 * 1024;
  const float4* xr1 = x4 + (size_t)(n0 + 1) * 1024;
  ushort4* xo0 = (ushort4*)(xb + (size_t)n0 * DIM);
  ushort4* xo1 = (ushort4*)(xb + (size_t)(n0 + 1) * DIM);

  float s0[NEXP] = {}, s1[NEXP] = {};
#pragma unroll 4
  for (int it = 0; it < 16; ++it) {
    const int col = it * 64 + lane;  // float4 column index; lanes coalesced
    float4 xv0 = xr0[col];
    float4 xv1 = xr1[col];
    ushort4 o0, o1;
    o0.x = f2bf(xv0.x); o0.y = f2bf(xv0.y); o0.z = f2bf(xv0.z); o0.w = f2bf(xv0.w);
    o1.x = f2bf(xv1.x); o1.y = f2bf(xv1.y); o1.z = f2bf(xv1.z); o1.w = f2bf(xv1.w);
    xo0[col] = o0;
    xo1[col] = o1;
#pragma unroll
    for (int e = 0; e < NEXP; ++e) {
      float4 wv4 = w4[(size_t)e * 1024 + col];  // L2-resident (128 KB total)
      s0[e] += xv0.x * wv4.x + xv0.y * wv4.y + xv0.z * wv4.z + xv0.w * wv4.w;
      s1[e] += xv1.x * wv4.x + xv1.y * wv4.y + xv1.z * wv4.z + xv1.w * wv4.w;
    }
  }
  // one butterfly per wave (96 DS ops for 8192 loaded floats)
#pragma unroll
  for (int m = 1; m < 64; m <<= 1)
#pragma unroll
    for (int e = 0; e < NEXP; ++e) {
      s0[e] += __shfl_xor(s0[e], m, 64);
      s1[e] += __shfl_xor(s1[e], m, 64);
    }
  if (lane == 0)      router_finalize(n0,     s0, br, gw, sel);
  else if (lane == 1) router_finalize(n0 + 1, s1, br, gw, sel);
}

// ---------------------------------------------------------------- listbuild
// Ballot-aggregated expert-list compaction. 16 blocks x 512 thr, 1 token/thr.
__global__ __launch_bounds__(512) void listbuild_kernel(
    const int* __restrict__ sel, int* __restrict__ lists,
    int* __restrict__ cnt) {
  __shared__ int blkCnt[NEXP];
  __shared__ int gBase[NEXP];
  __shared__ int waveOff[8][NEXP];
  const int tid = threadIdx.x;
  const int wv = tid >> 6, lane = tid & 63;
  const int n = blockIdx.x * 512 + tid;
  if (tid < NEXP) blkCnt[tid] = 0;
  __syncthreads();
  const int s = sel[n];
  const int i0 = s & 15, i1 = (s >> 4) & 15;
#pragma unroll
  for (int e = 0; e < NEXP; ++e) {
    unsigned long long m0 = __ballot(i0 == e);
    unsigned long long m1 = __ballot(i1 == e);
    if (lane == 0)
      waveOff[wv][e] = atomicAdd(&blkCnt[e], __popcll(m0) + __popcll(m1));
  }
  __syncthreads();
  if (tid < NEXP) gBase[tid] = atomicAdd(&cnt[tid], blkCnt[tid]);
  __syncthreads();
  const unsigned long long lt = (1ull << lane) - 1;
#pragma unroll
  for (int e = 0; e < NEXP; ++e) {
    unsigned long long m0 = __ballot(i0 == e);
    unsigned long long m1 = __ballot(i1 == e);
    int base = gBase[e] + waveOff[wv][e];
    if (i0 == e) lists[e * N_TOK + base + (int)__popcll(m0 & lt)] = n * 2;
    if (i1 == e)
      lists[e * N_TOK + base + (int)__popcll(m0) + (int)__popcll(m1 & lt)] =
          n * 2 + 1;
  }
}

// ---------------------------------------------------------------- GEMM1
// Per expert: h[entry, r] = xb[token] . Ab[e][r], scaled by gate*SCAL -> G bf16.
// Tile: 64 entries x 128 (full R), BK=32, 256 thr (4 waves 2x2, each 32x64).
// R1 post-mortem: old BK=64 drain-per-step structure at ~1 block/CU (only
// ~256 working blocks) was latency-bound: MfmaUtil 5.9 / VALU 2.8 / HBM 11%,
// occupancy 9.3%, plus the same [*][64] 16-way bank conflict gemm2 had
// (9.6e6 SQ_LDS_BANK_CONFLICT). Port of the gemm2 recipe: 4-slot LDS ring
// (A 4KB + B 8KB per slot = 48 KB), prefetch depth 3, UNIFORM 3 loads per
// wave per stage so counted s_waitcnt vmcnt(6) is per-wave exact; raw
// s_barrier only (no vmcnt(0) drain in the 128-step main loop); setprio
// around the MFMA cluster. BK=32 rows are 64 B so each frag ds_read_b128
// (16 rows x 4 quads) covers a contiguous 1 KiB block -> conflict-free.
// Race-freedom: tile kt lives in slot kt&3. STAGE(t+3) is issued after the
// PIPE_WAIT barrier of iter t, which follows the PIPE_END barrier of iter
// t-1, which follows all waves' reads of slot (t-1)&3 == (t+3)&3. Reads of
// tile t are safe: every wave did vmcnt(6) (own 3 t-loads landed, only
// t+1/t+2's 6 outstanding) before the same barrier.
__global__ __launch_bounds__(256) void gemm1_kernel(
    const u16* __restrict__ xb, const u16* __restrict__ Ab,
    const int* __restrict__ lists, const int* __restrict__ cnt,
    const float* __restrict__ gw, u16* __restrict__ G) {
  const int e = blockIdx.y;
  const int mt = blockIdx.x;
  const int c = cnt[e];
  if (mt * 64 >= c) return;

  __shared__ alignas(16) u16 ringA[4][64 * 32];    // 4 KB per slot
  __shared__ alignas(16) u16 ringB[4][128 * 32];   // 8 KB per slot
  __shared__ int   tokS[64];
  __shared__ float wS[64];

  const int tid = threadIdx.x;
  if (tid < 64) {
    int idx = mt * 64 + tid;
    int ci = idx < c ? idx : (c - 1);
    int entry = lists[e * N_TOK + ci];
    tokS[tid] = entry >> 1;
    wS[tid] = (idx < c) ? gw[entry] : 0.0f;
  }
  __syncthreads();

  const int srow = tid >> 2;        // staging row 0..63
  const int scol = (tid & 3) * 8;   // 16B column group within BK=32
  const u16* gA  = xb + (size_t)tokS[srow] * DIM + scol;
  const u16* gB0 = Ab + (size_t)e * (RANK * DIM) + (size_t)srow * DIM + scol;
  const u16* gB1 = gB0 + (size_t)64 * DIM;

  const int lane = tid & 63, wvi = tid >> 6;
  const int wm = wvi >> 1, wn = wvi & 1;
  const int m16 = lane & 15, quad = lane >> 4;

  f32x4 acc[2][4] = {};

  auto STAGE = [&](int kt, int slot) {
    const int k0 = kt * 32;
    async16(&ringA[slot][tid * 8],        gA  + k0);   // 3 loads per wave,
    async16(&ringB[slot][tid * 8],        gB0 + k0);   // uniform across waves
    async16(&ringB[slot][tid * 8 + 2048], gB1 + k0);   // (vmcnt correctness)
  };

  auto COMPUTE = [&](int slot) {
    bf16x8 af[2], bfr[4];
#pragma unroll
    for (int j = 0; j < 4; ++j)
      bfr[j] = *(const bf16x8*)&ringB[slot][(wn * 64 + j * 16 + m16) * 32 + quad * 8];
#pragma unroll
    for (int i = 0; i < 2; ++i)
      af[i] = *(const bf16x8*)&ringA[slot][(wm * 32 + i * 16 + m16) * 32 + quad * 8];
    __builtin_amdgcn_s_setprio(1);  // T5: favor the MFMA cluster
#pragma unroll
    for (int i = 0; i < 2; ++i)
#pragma unroll
      for (int j = 0; j < 4; ++j) acc[i][j] = mfma16(af[i], bfr[j], acc[i][j]);
    __builtin_amdgcn_s_setprio(0);
  };

  // Prologue: fill 3 of 4 ring slots (9 loads/wave in flight).
  STAGE(0, 0);
  STAGE(1, 1);
  STAGE(2, 2);

  // Main loop: 128 K-tiles (DIM/32). vmcnt(6) = tiles t+1,t+2 stay in flight.
  for (int t = 0; t < 125; ++t) {
    PIPE_WAIT(6);
    STAGE(t + 3, (t + 3) & 3);  // overlapped with compute below
    COMPUTE(t & 3);
    PIPE_END();
  }
  PIPE_WAIT(6); COMPUTE(1); PIPE_END();  // t=125
  PIPE_WAIT(3); COMPUTE(2); PIPE_END();  // t=126
  PIPE_WAIT(0); COMPUTE(3); PIPE_END();  // t=127

#pragma unroll
  for (int i = 0; i < 2; ++i)
#pragma unroll
    for (int rr = 0; rr < 4; ++rr) {
      int row = wm * 32 + i * 16 + quad * 4 + rr;  // C/D: row=quad*4+reg
      if (mt * 64 + row < c) {
        int tk = tokS[row];
        float wgt = wS[row];
        u16* gp = G + (size_t)tk * EK + e * RANK + wn * 64 + m16;  // col=lane&15
#pragma unroll
        for (int j = 0; j < 4; ++j) gp[j * 16] = f2bf(acc[i][j][rr] * wgt);
      }
    }
}

// ---------------------------------------------------------------- GEMM2
// Dense: out[8192,4096] = G[8192,1024] @ Bt[4096,1024]^T.
// 256x256 tile, BK=32, 512 thr (8 waves 2x4, each 128x64 of C).
// 4-slot LDS ring (128 KiB), prefetch depth 3, counted s_waitcnt vmcnt(8) —
// loads NEVER drain to 0 in the main loop (T3+T4). Raw s_barrier only.
__global__ __launch_bounds__(512, 2) void gemm2_kernel(
    const u16* __restrict__ G, const u16* __restrict__ Bt,
    float* __restrict__ out) {
  __shared__ alignas(16) u16 ring[4][2][256 * 32];  // 4 x (A 16KB + B 16KB)

  // T1: bijective XCD swizzle (512 wgs, 512 % 8 == 0). XCD x gets a
  // contiguous band of 4 m-tiles (1024 G rows = 2 MB, L2-resident).
  const int lin = blockIdx.y * 16 + blockIdx.x;
  const int swz = (lin & 7) * 64 + (lin >> 3);
  const int by = swz >> 4;  // m-tile 0..31
  const int bx = swz & 15;  // n-tile 0..15

  const int tid = threadIdx.x;
  const int sr = tid >> 2;        // staging row 0..127 within half
  const int sc = (tid & 3) * 8;   // staging 16B col group
  const u16* gA = G  + (size_t)(by * 256 + sr) * EK + sc;
  const u16* gB = Bt + (size_t)(bx * 256 + sr) * EK + sc;

  const int lane = tid & 63, wvi = tid >> 6;  // 8 waves
  const int wm = wvi >> 2, wn = wvi & 3;      // 2 x 4 wave grid
  const int m16 = lane & 15, quad = lane >> 4;

  f32x4 acc[8][4] = {};

  auto STAGE = [&](int kt, int slot) {
    u16* lA = &ring[slot][0][tid * 8];   // linear dest = base + tid*16B
    u16* lB = &ring[slot][1][tid * 8];
    const u16* sA = gA + kt * 32;
    const u16* sB = gB + kt * 32;
    async16(lA,        sA);
    async16(lA + 4096, sA + (size_t)128 * EK);
    async16(lB,        sB);
    async16(lB + 4096, sB + (size_t)128 * EK);
  };

  auto COMPUTE = [&](int slot) {
    const u16* As_ = &ring[slot][0][0];
    const u16* Bs_ = &ring[slot][1][0];
    bf16x8 bfr[4];
#pragma unroll
    for (int j = 0; j < 4; ++j)
      bfr[j] = *(const bf16x8*)&Bs_[(wn * 64 + j * 16 + m16) * 32 + quad * 8];
    __builtin_amdgcn_s_setprio(1);  // T5: favor the MFMA cluster
#pragma unroll
    for (int i = 0; i < 8; ++i) {
      bf16x8 af = *(const bf16x8*)&As_[(wm * 128 + i * 16 + m16) * 32 + quad * 8];
#pragma unroll
      for (int j = 0; j < 4; ++j) acc[i][j] = mfma16(af, bfr[j], acc[i][j]);
    }
    __builtin_amdgcn_s_setprio(0);
  };

  // Prologue: fill 3 of 4 ring slots (12 loads in flight).
  STAGE(0, 0);
  STAGE(1, 1);
  STAGE(2, 2);

  // Main loop: 32 K-tiles (EK/32). vmcnt(8) = tiles t+1,t+2 stay in flight.
  for (int t = 0; t < 29; ++t) {
    PIPE_WAIT(8);
    STAGE(t + 3, (t + 3) & 3);  // overlapped with compute below
    COMPUTE(t & 3);
    PIPE_END();
  }
  PIPE_WAIT(8); COMPUTE(1); PIPE_END();  // t=29
  PIPE_WAIT(4); COMPUTE(2); PIPE_END();  // t=30
  PIPE_WAIT(0); COMPUTE(3); PIPE_END();  // t=31

#pragma unroll
  for (int i = 0; i < 8; ++i)
#pragma unroll
    for (int rr = 0; rr < 4; ++rr) {
      int row = by * 256 + wm * 128 + i * 16 + quad * 4 + rr;
      float* op = out + (size_t)row * DIM + bx * 256 + wn * 64 + m16;
#pragma unroll
      for (int j = 0; j < 4; ++j) op[j * 16] = acc[i][j][rr];
    }
}

// ---------------------------------------------------------------- launch
extern "C" void kernel_launch(void* const* d_in, const int* in_sizes, int n_in,
                              void* d_out, int out_size, void* d_ws, size_t ws_size,
                              hipStream_t stream) {
  const float* x  = (const float*)d_in[0];
  const float* Wr = (const float*)d_in[1];
  const float* br = (const float*)d_in[2];
  const float* A  = (const float*)d_in[3];
  const float* B  = (const float*)d_in[4];
  float* out = (float*)d_out;

  char* w = (char*)d_ws;
  u16* xb = (u16*)w;      w += (size_t)N_TOK * DIM * 2;        // 67.1 MB
  u16* G  = (u16*)w;      w += (size_t)N_TOK * EK * 2;         // 16.8 MB
  u16* Ab = (u16*)w;      w += (size_t)NEXP * RANK * DIM * 2;  //  8.4 MB
  u16* Bt = (u16*)w;      w += (size_t)DIM * EK * 2;           //  8.4 MB
  float* gw = (float*)w;  w += (size_t)N_TOK * 2 * 4;          // 64 KB
  int* lists = (int*)w;   w += (size_t)NEXP * N_TOK * 4;       // 256 KB
  int* sel = (int*)w;     w += (size_t)N_TOK * 4;              // 32 KB
  int* cnt = (int*)w;     w += 256;

  hipMemsetAsync(cnt, 0, NEXP * sizeof(int), stream);
  hipMemsetAsync(G, 0, (size_t)N_TOK * EK * 2, stream);  // unselected blocks = 0

  cvtA_kernel<<<dim3(4096), dim3(256), 0, stream>>>(A, Ab);
  cvtB_kernel<<<dim3(4096), dim3(256), 0, stream>>>(B, Bt);
  router_kernel<<<dim3(1024), dim3(256), 0, stream>>>(x, Wr, br, xb, gw, sel);
  listbuild_kernel<<<dim3(16), dim3(512), 0, stream>>>(sel, lists, cnt);
  gemm1_kernel<<<dim3(128, NEXP), dim3(256), 0, stream>>>(xb, Ab, lists, cnt, gw, G);
  gemm2_kernel<<<dim3(16, 32), dim3(512), 0, stream>>>(G, Bt, out);
}

// Round 4
// 446.349 us; speedup vs baseline: 1.1229x; 1.0007x over previous
//
#include <hip/hip_runtime.h>

// Problem constants
#define N_TOK 8192
#define DIM   4096
#define NEXP  8
#define RANK  128
#define EK    (NEXP * RANK)   // 1024 = flattened (expert, rank) K dim for GEMM2
#define SCAL  0.25f           // LORA_ALPHA / R = 32/128

typedef unsigned short u16;
typedef __bf16 bf16x8 __attribute__((ext_vector_type(8)));
typedef float  f32x4  __attribute__((ext_vector_type(4)));

typedef const __attribute__((address_space(1))) void* as1_cvp;
typedef __attribute__((address_space(3))) void*       as3_vp;

__device__ __forceinline__ void async16(void* lds, const void* g) {
  // 16B-per-lane direct global->LDS (global_load_lds_dwordx4). LDS dest must be
  // wave-uniform base + lane*16 — all call sites arrange lds = base + tid*16B.
  __builtin_amdgcn_global_load_lds((as1_cvp)g, (as3_vp)lds, 16, 0, 0);
}

__device__ __forceinline__ u16 f2bf(float f) {  // RNE float->bf16 bits
  unsigned int u = __builtin_bit_cast(unsigned int, f);
  u += 0x7fffu + ((u >> 16) & 1u);
  return (u16)(u >> 16);
}

__device__ __forceinline__ f32x4 mfma16(bf16x8 a, bf16x8 b, f32x4 c) {
  return __builtin_amdgcn_mfma_f32_16x16x32_bf16(a, b, c, 0, 0, 0);
}

// Counted-vmcnt pipeline fences. Raw s_barrier — __syncthreads would emit
// s_waitcnt vmcnt(0) and drain the prefetch queue (the m97 ~20% stall).
// sched_barrier(0) pins compiler scheduling at the fence (rule #18 analog).
#define PIPE_WAIT(N)                                            \
  __builtin_amdgcn_sched_barrier(0);                            \
  asm volatile("s_waitcnt vmcnt(" #N ")" ::: "memory");         \
  __builtin_amdgcn_s_barrier();                                 \
  __builtin_amdgcn_sched_barrier(0)

#define PIPE_END()                                              \
  __builtin_amdgcn_sched_barrier(0);                            \
  __builtin_amdgcn_s_barrier();                                 \
  __builtin_amdgcn_sched_barrier(0)

// ---------------------------------------------------------------- converts
__global__ __launch_bounds__(256) void cvtA_kernel(const float* __restrict__ A,
                                                   u16* __restrict__ Ab) {
  size_t i = (size_t)blockIdx.x * 256 + threadIdx.x;  // float4 index, same layout
  float4 v = ((const float4*)A)[i];
  ushort4 o;
  o.x = f2bf(v.x); o.y = f2bf(v.y); o.z = f2bf(v.z); o.w = f2bf(v.w);
  ((ushort4*)Ab)[i] = o;
}

// B[e][o][r] fp32 -> Bt[o][e*128+r] bf16 (BT layout for GEMM2, k-contiguous rows)
__global__ __launch_bounds__(256) void cvtB_kernel(const float* __restrict__ B,
                                                   u16* __restrict__ Bt) {
  size_t i = (size_t)blockIdx.x * 256 + threadIdx.x;  // enumerates (e, o, r/4)
  int r4 = (int)(i & 31);
  int o_ = (int)((i >> 5) & 4095);
  int e  = (int)(i >> 17);
  float4 v = ((const float4*)B)[i];
  ushort4 u;
  u.x = f2bf(v.x); u.y = f2bf(v.y); u.z = f2bf(v.z); u.w = f2bf(v.w);
  ((ushort4*)Bt)[(size_t)o_ * 256 + e * 32 + r4] = u;
}

// ---------------------------------------------------------------- router
// fp32 router (bf16 would flip near-tie expert picks), fused x->bf16 convert.
__device__ __forceinline__ void router_finalize(
    int n, const float* l_in, const float* __restrict__ br,
    float* __restrict__ gw, int* __restrict__ sel) {
  float l[NEXP];
#pragma unroll
  for (int e = 0; e < NEXP; ++e) l[e] = l_in[e] + br[e];
  int i0 = 0;
#pragma unroll
  for (int e = 1; e < NEXP; ++e) if (l[e] > l[i0]) i0 = e;
  int i1 = (i0 == 0) ? 1 : 0;
#pragma unroll
  for (int e = 0; e < NEXP; ++e) if (e != i0 && l[e] > l[i1]) i1 = e;
  // renormalized top-2 gate: w0 = exp(l0)/(exp(l0)+exp(l1)); l1<=l0 so no ovf
  float w0 = 1.f / (1.f + expf(l[i1] - l[i0]));
  gw[n * 2 + 0] = w0 * SCAL;
  gw[n * 2 + 1] = (1.f - w0) * SCAL;
  sel[n] = i0 | (i1 << 4);
}

// R2 post-mortem: old per-wave structure was latency-bound (95us, HBM 17.6%,
// VALU 11.7%, 40 VGPR): compiler serialized the 160 loads/wave into tiny
// issue/wait groups, 80% of them L2-hit Wr re-reads (128 KB per 2 tokens).
// R3 (crashed): the router rewrite below never ran — the crash was an OOB
// from a stale gemm2 launch line (dim3(32,64)x256 against the 512-thread
// 256^2-tile kernel -> by up to 36 -> rows past out). R4 = R3 with the
// launch line fixed to dim3(16,32)x512.
// Router structure: counted-vmcnt ring (gemm recipe). 512 blocks x 256 thr,
// 4 tokens/wave. K-chunk = 512 floats; Wr chunk (8e x 512 = 16 KB) double-
// buffered in LDS via 4 async16 rounds; x in double-buffered named register
// arrays (rule #20: macros give static indexing). Each wave issues EXACTLY
// 12 VMEM ops per chunk (4 stage + 8 x-loads), then vmcnt(12)+s_barrier:
// previous chunk landed, next chunk's 12 stay in flight — never drains to 0
// mid-loop. vmcnt(12) also retires the prior compute's 8 xb stores (queue:
// [chunk t loads 12][t-1 stores 8][t+1 loads 12] -> drain 20 oldest).
// Buffer safety: stage into buf B at top of t targets the buffer last read
// at compute t-2, which finished before the PIPE_END barrier of t-2 < top t.
#define R_STAGE(kc, buf)                                                    \
  {                                                                         \
    const int k0_ = (kc) * 512;                                             \
    _Pragma("unroll")                                                       \
    for (int r_ = 0; r_ < 4; ++r_)                                          \
      async16(&WrL[buf][r_ * 1024 + tid * 4],                               \
              wsrc + (size_t)(2 * r_) * DIM + k0_);                         \
  }

#define R_LOADX(kc, xv)                                                     \
  {                                                                         \
    const int kb_ = (kc) * 128;                                             \
    _Pragma("unroll")                                                       \
    for (int t_ = 0; t_ < 4; ++t_)                                          \
      _Pragma("unroll")                                                     \
      for (int c_ = 0; c_ < 2; ++c_)                                        \
        xv[t_][c_] = x4[(size_t)(tok0 + t_) * 1024 + kb_ + c_ * 64 + lane]; \
  }

#define R_COMPUTE(kc, buf, xv)                                              \
  {                                                                         \
    const float4* WL_ = (const float4*)WrL[buf];                            \
    _Pragma("unroll")                                                       \
    for (int c_ = 0; c_ < 2; ++c_) {                                        \
      float4 wr_[8];                                                        \
      _Pragma("unroll")                                                     \
      for (int e_ = 0; e_ < 8; ++e_)                                        \
        wr_[e_] = WL_[e_ * 128 + c_ * 64 + lane];                           \
      _Pragma("unroll")                                                     \
      for (int t_ = 0; t_ < 4; ++t_)                                        \
        _Pragma("unroll")                                                   \
        for (int e_ = 0; e_ < 8; ++e_)                                      \
          sums[t_][e_] += xv[t_][c_].x * wr_[e_].x + xv[t_][c_].y * wr_[e_].y + \
                          xv[t_][c_].z * wr_[e_].z + xv[t_][c_].w * wr_[e_].w;  \
    }                                                                       \
    const int kb_ = (kc) * 128;                                             \
    _Pragma("unroll")                                                       \
    for (int t_ = 0; t_ < 4; ++t_) {                                        \
      ushort4* xo_ = (ushort4*)(xb + (size_t)(tok0 + t_) * DIM);            \
      _Pragma("unroll")                                                     \
      for (int c_ = 0; c_ < 2; ++c_) {                                      \
        float4 v_ = xv[t_][c_];                                             \
        ushort4 o_;                                                         \
        o_.x = f2bf(v_.x); o_.y = f2bf(v_.y);                               \
        o_.z = f2bf(v_.z); o_.w = f2bf(v_.w);                               \
        xo_[kb_ + c_ * 64 + lane] = o_;                                     \
      }                                                                     \
    }                                                                       \
  }

__global__ __launch_bounds__(256, 2) void router_kernel(
    const float* __restrict__ x, const float* __restrict__ Wr,
    const float* __restrict__ br, u16* __restrict__ xb,
    float* __restrict__ gw, int* __restrict__ sel) {
  __shared__ alignas(16) float WrL[2][4096];  // 2 x (8 experts x 512 f) = 32 KB

  const int tid = threadIdx.x;
  const int wv = tid >> 6, lane = tid & 63;
  const int tok0 = blockIdx.x * 16 + wv * 4;  // this wave's 4 tokens

  const float4* x4 = (const float4*)x;
  // Staging source: round r covers experts {2r, 2r+1}; thread t takes expert
  // 2r + (t>>7), floats (t&127)*4. Per wave the global src is contiguous and
  // the LDS dest is base + lane*16 (linear) — async16 constraint satisfied.
  const float* wsrc = Wr + (size_t)(tid >> 7) * DIM + (tid & 127) * 4;

  float4 xvA[4][2], xvB[4][2];
  float sums[4][8] = {};

  R_STAGE(0, 0); R_LOADX(0, xvA);
  for (int kc = 0; kc < 3; ++kc) {   // chunks 2kc, 2kc+1
    R_STAGE(2 * kc + 1, 1); R_LOADX(2 * kc + 1, xvB);
    PIPE_WAIT(12);
    R_COMPUTE(2 * kc, 0, xvA);
    PIPE_END();
    R_STAGE(2 * kc + 2, 0); R_LOADX(2 * kc + 2, xvA);
    PIPE_WAIT(12);
    R_COMPUTE(2 * kc + 1, 1, xvB);
    PIPE_END();
  }
  R_STAGE(7, 1); R_LOADX(7, xvB);
  PIPE_WAIT(12);
  R_COMPUTE(6, 0, xvA);
  PIPE_END();
  PIPE_WAIT(0);
  R_COMPUTE(7, 1, xvB);

  // Full-wave butterfly: every lane ends with complete sums for all 4 tokens.
#pragma unroll
  for (int m = 1; m < 64; m <<= 1)
#pragma unroll
    for (int t = 0; t < 4; ++t)
#pragma unroll
      for (int e = 0; e < 8; ++e)
        sums[t][e] += __shfl_xor(sums[t][e], m, 64);

  if (lane < 4) {
    float fl[8];  // static-index select (rule #20: no runtime reg-array index)
#pragma unroll
    for (int e = 0; e < 8; ++e)
      fl[e] = lane == 0 ? sums[0][e]
            : lane == 1 ? sums[1][e]
            : lane == 2 ? sums[2][e] : sums[3][e];
    router_finalize(tok0 + lane, fl, br, gw, sel);
  }
}

// ---------------------------------------------------------------- listbuild
// Ballot-aggregated expert-list compaction. 16 blocks x 512 thr, 1 token/thr.
__global__ __launch_bounds__(512) void listbuild_kernel(
    const int* __restrict__ sel, int* __restrict__ lists,
    int* __restrict__ cnt) {
  __shared__ int blkCnt[NEXP];
  __shared__ int gBase[NEXP];
  __shared__ int waveOff[8][NEXP];
  const int tid = threadIdx.x;
  const int wv = tid >> 6, lane = tid & 63;
  const int n = blockIdx.x * 512 + tid;
  if (tid < NEXP) blkCnt[tid] = 0;
  __syncthreads();
  const int s = sel[n];
  const int i0 = s & 15, i1 = (s >> 4) & 15;
#pragma unroll
  for (int e = 0; e < NEXP; ++e) {
    unsigned long long m0 = __ballot(i0 == e);
    unsigned long long m1 = __ballot(i1 == e);
    if (lane == 0)
      waveOff[wv][e] = atomicAdd(&blkCnt[e], __popcll(m0) + __popcll(m1));
  }
  __syncthreads();
  if (tid < NEXP) gBase[tid] = atomicAdd(&cnt[tid], blkCnt[tid]);
  __syncthreads();
  const unsigned long long lt = (1ull << lane) - 1;
#pragma unroll
  for (int e = 0; e < NEXP; ++e) {
    unsigned long long m0 = __ballot(i0 == e);
    unsigned long long m1 = __ballot(i1 == e);
    int base = gBase[e] + waveOff[wv][e];
    if (i0 == e) lists[e * N_TOK + base + (int)__popcll(m0 & lt)] = n * 2;
    if (i1 == e)
      lists[e * N_TOK + base + (int)__popcll(m0) + (int)__popcll(m1 & lt)] =
          n * 2 + 1;
  }
}

// ---------------------------------------------------------------- GEMM1
// Per expert: h[entry, r] = xb[token] . Ab[e][r], scaled by gate*SCAL -> G bf16.
// Tile: 64 entries x 128 (full R), BK=32, 256 thr (4 waves 2x2, each 32x64).
// 4-slot LDS ring, prefetch depth 3, uniform 3 loads/wave/stage, vmcnt(6).
__global__ __launch_bounds__(256) void gemm1_kernel(
    const u16* __restrict__ xb, const u16* __restrict__ Ab,
    const int* __restrict__ lists, const int* __restrict__ cnt,
    const float* __restrict__ gw, u16* __restrict__ G) {
  const int e = blockIdx.y;
  const int mt = blockIdx.x;
  const int c = cnt[e];
  if (mt * 64 >= c) return;

  __shared__ alignas(16) u16 ringA[4][64 * 32];    // 4 KB per slot
  __shared__ alignas(16) u16 ringB[4][128 * 32];   // 8 KB per slot
  __shared__ int   tokS[64];
  __shared__ float wS[64];

  const int tid = threadIdx.x;
  if (tid < 64) {
    int idx = mt * 64 + tid;
    int ci = idx < c ? idx : (c - 1);
    int entry = lists[e * N_TOK + ci];
    tokS[tid] = entry >> 1;
    wS[tid] = (idx < c) ? gw[entry] : 0.0f;
  }
  __syncthreads();

  const int srow = tid >> 2;        // staging row 0..63
  const int scol = (tid & 3) * 8;   // 16B column group within BK=32
  const u16* gA  = xb + (size_t)tokS[srow] * DIM + scol;
  const u16* gB0 = Ab + (size_t)e * (RANK * DIM) + (size_t)srow * DIM + scol;
  const u16* gB1 = gB0 + (size_t)64 * DIM;

  const int lane = tid & 63, wvi = tid >> 6;
  const int wm = wvi >> 1, wn = wvi & 1;
  const int m16 = lane & 15, quad = lane >> 4;

  f32x4 acc[2][4] = {};

  auto STAGE = [&](int kt, int slot) {
    const int k0 = kt * 32;
    async16(&ringA[slot][tid * 8],        gA  + k0);   // 3 loads per wave,
    async16(&ringB[slot][tid * 8],        gB0 + k0);   // uniform across waves
    async16(&ringB[slot][tid * 8 + 2048], gB1 + k0);   // (vmcnt correctness)
  };

  auto COMPUTE = [&](int slot) {
    bf16x8 af[2], bfr[4];
#pragma unroll
    for (int j = 0; j < 4; ++j)
      bfr[j] = *(const bf16x8*)&ringB[slot][(wn * 64 + j * 16 + m16) * 32 + quad * 8];
#pragma unroll
    for (int i = 0; i < 2; ++i)
      af[i] = *(const bf16x8*)&ringA[slot][(wm * 32 + i * 16 + m16) * 32 + quad * 8];
    __builtin_amdgcn_s_setprio(1);  // T5: favor the MFMA cluster
#pragma unroll
    for (int i = 0; i < 2; ++i)
#pragma unroll
      for (int j = 0; j < 4; ++j) acc[i][j] = mfma16(af[i], bfr[j], acc[i][j]);
    __builtin_amdgcn_s_setprio(0);
  };

  // Prologue: fill 3 of 4 ring slots (9 loads/wave in flight).
  STAGE(0, 0);
  STAGE(1, 1);
  STAGE(2, 2);

  // Main loop: 128 K-tiles (DIM/32). vmcnt(6) = tiles t+1,t+2 stay in flight.
  for (int t = 0; t < 125; ++t) {
    PIPE_WAIT(6);
    STAGE(t + 3, (t + 3) & 3);  // overlapped with compute below
    COMPUTE(t & 3);
    PIPE_END();
  }
  PIPE_WAIT(6); COMPUTE(1); PIPE_END();  // t=125
  PIPE_WAIT(3); COMPUTE(2); PIPE_END();  // t=126
  PIPE_WAIT(0); COMPUTE(3); PIPE_END();  // t=127

#pragma unroll
  for (int i = 0; i < 2; ++i)
#pragma unroll
    for (int rr = 0; rr < 4; ++rr) {
      int row = wm * 32 + i * 16 + quad * 4 + rr;  // C/D: row=quad*4+reg
      if (mt * 64 + row < c) {
        int tk = tokS[row];
        float wgt = wS[row];
        u16* gp = G + (size_t)tk * EK + e * RANK + wn * 64 + m16;  // col=lane&15
#pragma unroll
        for (int j = 0; j < 4; ++j) gp[j * 16] = f2bf(acc[i][j][rr] * wgt);
      }
    }
}

// ---------------------------------------------------------------- GEMM2
// Dense: out[8192,4096] = G[8192,1024] @ Bt[4096,1024]^T.
// 256x256 tile, BK=32, 512 thr (8 waves 2x4, each 128x64 of C).
// 4-slot LDS ring (128 KiB), prefetch depth 3, counted s_waitcnt vmcnt(8) —
// loads NEVER drain to 0 in the main loop (T3+T4). Raw s_barrier only.
// LAUNCH MUST BE dim3(16,32) x 512 — R3's crash was a stale dim3(32,64)x256
// launch of this kernel (half-staged tile + swizzle OOB on out rows).
__global__ __launch_bounds__(512, 2) void gemm2_kernel(
    const u16* __restrict__ G, const u16* __restrict__ Bt,
    float* __restrict__ out) {
  __shared__ alignas(16) u16 ring[4][2][256 * 32];  // 4 x (A 16KB + B 16KB)

  // T1: bijective XCD swizzle (512 wgs, 512 % 8 == 0). XCD x gets a
  // contiguous band of 4 m-tiles (1024 G rows = 2 MB, L2-resident).
  const int lin = blockIdx.y * 16 + blockIdx.x;
  const int swz = (lin & 7) * 64 + (lin >> 3);
  const int by = swz >> 4;  // m-tile 0..31
  const int bx = swz & 15;  // n-tile 0..15

  const int tid = threadIdx.x;
  const int sr = tid >> 2;        // staging row 0..127 within half
  const int sc = (tid & 3) * 8;   // staging 16B col group
  const u16* gA = G  + (size_t)(by * 256 + sr) * EK + sc;
  const u16* gB = Bt + (size_t)(bx * 256 + sr) * EK + sc;

  const int lane = tid & 63, wvi = tid >> 6;  // 8 waves
  const int wm = wvi >> 2, wn = wvi & 3;      // 2 x 4 wave grid
  const int m16 = lane & 15, quad = lane >> 4;

  f32x4 acc[8][4] = {};

  auto STAGE = [&](int kt, int slot) {
    u16* lA = &ring[slot][0][tid * 8];   // linear dest = base + tid*16B
    u16* lB = &ring[slot][1][tid * 8];
    const u16* sA = gA + kt * 32;
    const u16* sB = gB + kt * 32;
    async16(lA,        sA);
    async16(lA + 4096, sA + (size_t)128 * EK);
    async16(lB,        sB);
    async16(lB + 4096, sB + (size_t)128 * EK);
  };

  auto COMPUTE = [&](int slot) {
    const u16* As_ = &ring[slot][0][0];
    const u16* Bs_ = &ring[slot][1][0];
    bf16x8 bfr[4];
#pragma unroll
    for (int j = 0; j < 4; ++j)
      bfr[j] = *(const bf16x8*)&Bs_[(wn * 64 + j * 16 + m16) * 32 + quad * 8];
    __builtin_amdgcn_s_setprio(1);  // T5: favor the MFMA cluster
#pragma unroll
    for (int i = 0; i < 8; ++i) {
      bf16x8 af = *(const bf16x8*)&As_[(wm * 128 + i * 16 + m16) * 32 + quad * 8];
#pragma unroll
      for (int j = 0; j < 4; ++j) acc[i][j] = mfma16(af, bfr[j], acc[i][j]);
    }
    __builtin_amdgcn_s_setprio(0);
  };

  // Prologue: fill 3 of 4 ring slots (12 loads in flight).
  STAGE(0, 0);
  STAGE(1, 1);
  STAGE(2, 2);

  // Main loop: 32 K-tiles (EK/32). vmcnt(8) = tiles t+1,t+2 stay in flight.
  for (int t = 0; t < 29; ++t) {
    PIPE_WAIT(8);
    STAGE(t + 3, (t + 3) & 3);  // overlapped with compute below
    COMPUTE(t & 3);
    PIPE_END();
  }
  PIPE_WAIT(8); COMPUTE(1); PIPE_END();  // t=29
  PIPE_WAIT(4); COMPUTE(2); PIPE_END();  // t=30
  PIPE_WAIT(0); COMPUTE(3); PIPE_END();  // t=31

#pragma unroll
  for (int i = 0; i < 8; ++i)
#pragma unroll
    for (int rr = 0; rr < 4; ++rr) {
      int row = by * 256 + wm * 128 + i * 16 + quad * 4 + rr;
      float* op = out + (size_t)row * DIM + bx * 256 + wn * 64 + m16;
#pragma unroll
      for (int j = 0; j < 4; ++j) op[j * 16] = acc[i][j][rr];
    }
}

// ---------------------------------------------------------------- launch
extern "C" void kernel_launch(void* const* d_in, const int* in_sizes, int n_in,
                              void* d_out, int out_size, void* d_ws, size_t ws_size,
                              hipStream_t stream) {
  const float* x  = (const float*)d_in[0];
  const float* Wr = (const float*)d_in[1];
  const float* br = (const float*)d_in[2];
  const float* A  = (const float*)d_in[3];
  const float* B  = (const float*)d_in[4];
  float* out = (float*)d_out;

  char* w = (char*)d_ws;
  u16* xb = (u16*)w;      w += (size_t)N_TOK * DIM * 2;        // 67.1 MB
  u16* G  = (u16*)w;      w += (size_t)N_TOK * EK * 2;         // 16.8 MB
  u16* Ab = (u16*)w;      w += (size_t)NEXP * RANK * DIM * 2;  //  8.4 MB
  u16* Bt = (u16*)w;      w += (size_t)DIM * EK * 2;           //  8.4 MB
  float* gw = (float*)w;  w += (size_t)N_TOK * 2 * 4;          // 64 KB
  int* lists = (int*)w;   w += (size_t)NEXP * N_TOK * 4;       // 256 KB
  int* sel = (int*)w;     w += (size_t)N_TOK * 4;              // 32 KB
  int* cnt = (int*)w;     w += 256;

  hipMemsetAsync(cnt, 0, NEXP * sizeof(int), stream);
  hipMemsetAsync(G, 0, (size_t)N_TOK * EK * 2, stream);  // unselected blocks = 0

  cvtA_kernel<<<dim3(4096), dim3(256), 0, stream>>>(A, Ab);
  cvtB_kernel<<<dim3(4096), dim3(256), 0, stream>>>(B, Bt);
  router_kernel<<<dim3(512), dim3(256), 0, stream>>>(x, Wr, br, xb, gw, sel);
  listbuild_kernel<<<dim3(16), dim3(512), 0, stream>>>(sel, lists, cnt);
  gemm1_kernel<<<dim3(128, NEXP), dim3(256), 0, stream>>>(xb, Ab, lists, cnt, gw, G);
  gemm2_kernel<<<dim3(16, 32), dim3(512), 0, stream>>>(G, Bt, out);
}

// Round 5
// 441.384 us; speedup vs baseline: 1.1356x; 1.0112x over previous
//
#include <hip/hip_runtime.h>

// Problem constants
#define N_TOK 8192
#define DIM   4096
#define NEXP  8
#define RANK  128
#define EK    (NEXP * RANK)   // 1024 = flattened (expert, rank) K dim for GEMM2
#define SCAL  0.25f           // LORA_ALPHA / R = 32/128

typedef unsigned short u16;
typedef __bf16 bf16x8 __attribute__((ext_vector_type(8)));
typedef float  f32x4  __attribute__((ext_vector_type(4)));

typedef const __attribute__((address_space(1))) void* as1_cvp;
typedef __attribute__((address_space(3))) void*       as3_vp;

__device__ __forceinline__ void async16(void* lds, const void* g) {
  // 16B-per-lane direct global->LDS (global_load_lds_dwordx4). LDS dest must be
  // wave-uniform base + lane*16 — all call sites arrange lds = base + tid*16B.
  __builtin_amdgcn_global_load_lds((as1_cvp)g, (as3_vp)lds, 16, 0, 0);
}

__device__ __forceinline__ u16 f2bf(float f) {  // RNE float->bf16 bits
  unsigned int u = __builtin_bit_cast(unsigned int, f);
  u += 0x7fffu + ((u >> 16) & 1u);
  return (u16)(u >> 16);
}

__device__ __forceinline__ f32x4 mfma16(bf16x8 a, bf16x8 b, f32x4 c) {
  return __builtin_amdgcn_mfma_f32_16x16x32_bf16(a, b, c, 0, 0, 0);
}

// Counted-vmcnt pipeline fences. Raw s_barrier — __syncthreads would emit
// s_waitcnt vmcnt(0) and drain the prefetch queue (the m97 ~20% stall).
// sched_barrier(0) pins compiler scheduling at the fence (rule #18 analog).
#define PIPE_WAIT(N)                                            \
  __builtin_amdgcn_sched_barrier(0);                            \
  asm volatile("s_waitcnt vmcnt(" #N ")" ::: "memory");         \
  __builtin_amdgcn_s_barrier();                                 \
  __builtin_amdgcn_sched_barrier(0)

#define PIPE_END()                                              \
  __builtin_amdgcn_sched_barrier(0);                            \
  __builtin_amdgcn_s_barrier();                                 \
  __builtin_amdgcn_sched_barrier(0)

// ---------------------------------------------------------------- converts
__global__ __launch_bounds__(256) void cvtA_kernel(const float* __restrict__ A,
                                                   u16* __restrict__ Ab) {
  size_t i = (size_t)blockIdx.x * 256 + threadIdx.x;  // float4 index, same layout
  float4 v = ((const float4*)A)[i];
  ushort4 o;
  o.x = f2bf(v.x); o.y = f2bf(v.y); o.z = f2bf(v.z); o.w = f2bf(v.w);
  ((ushort4*)Ab)[i] = o;
}

// B[e][o][r] fp32 -> Bt[o][e*128+r] bf16 (BT layout for GEMM2, k-contiguous rows)
__global__ __launch_bounds__(256) void cvtB_kernel(const float* __restrict__ B,
                                                   u16* __restrict__ Bt) {
  size_t i = (size_t)blockIdx.x * 256 + threadIdx.x;  // enumerates (e, o, r/4)
  int r4 = (int)(i & 31);
  int o_ = (int)((i >> 5) & 4095);
  int e  = (int)(i >> 17);
  float4 v = ((const float4*)B)[i];
  ushort4 u;
  u.x = f2bf(v.x); u.y = f2bf(v.y); u.z = f2bf(v.z); u.w = f2bf(v.w);
  ((ushort4*)Bt)[(size_t)o_ * 256 + e * 32 + r4] = u;
}

// ---------------------------------------------------------------- router
// fp32 router (bf16 would flip near-tie expert picks), fused x->bf16 convert.
__device__ __forceinline__ void router_finalize(
    int n, const float* l_in, const float* __restrict__ br,
    float* __restrict__ gw, int* __restrict__ sel) {
  float l[NEXP];
#pragma unroll
  for (int e = 0; e < NEXP; ++e) l[e] = l_in[e] + br[e];
  int i0 = 0;
#pragma unroll
  for (int e = 1; e < NEXP; ++e) if (l[e] > l[i0]) i0 = e;
  int i1 = (i0 == 0) ? 1 : 0;
#pragma unroll
  for (int e = 0; e < NEXP; ++e) if (e != i0 && l[e] > l[i1]) i1 = e;
  // renormalized top-2 gate: w0 = exp(l0)/(exp(l0)+exp(l1)); l1<=l0 so no ovf
  float w0 = 1.f / (1.f + expf(l[i1] - l[i0]));
  gw[n * 2 + 0] = w0 * SCAL;
  gw[n * 2 + 1] = (1.f - w0) * SCAL;
  sel[n] = i0 | (i1 << 4);
}

// R4 post-mortem: the 4-token/wave ring gained ~0 (router still ~93us).
// Theory: register state (xvA+xvB=64 + sums 32 + wr 32 + pipeline) blew the
// 128-VGPR cap from launch_bounds(256,2) -> scratch spills. R5: 2 tokens/wave
// (~48 regs of x state), 1024 blocks, 8 VMEM/wave/phase, vmcnt(8).
#define R_STAGE(kc, buf)                                                    \
  {                                                                         \
    const int k0_ = (kc) * 512;                                             \
    _Pragma("unroll")                                                       \
    for (int r_ = 0; r_ < 4; ++r_)                                          \
      async16(&WrL[buf][r_ * 1024 + tid * 4],                               \
              wsrc + (size_t)(2 * r_) * DIM + k0_);                         \
  }

#define R_LOADX(kc, xv)                                                     \
  {                                                                         \
    const int kb_ = (kc) * 128;                                             \
    _Pragma("unroll")                                                       \
    for (int t_ = 0; t_ < 2; ++t_)                                          \
      _Pragma("unroll")                                                     \
      for (int c_ = 0; c_ < 2; ++c_)                                        \
        xv[t_][c_] = x4[(size_t)(tok0 + t_) * 1024 + kb_ + c_ * 64 + lane]; \
  }

#define R_COMPUTE(kc, buf, xv)                                              \
  {                                                                         \
    const float4* WL_ = (const float4*)WrL[buf];                            \
    _Pragma("unroll")                                                       \
    for (int c_ = 0; c_ < 2; ++c_) {                                        \
      float4 wr_[8];                                                        \
      _Pragma("unroll")                                                     \
      for (int e_ = 0; e_ < 8; ++e_)                                        \
        wr_[e_] = WL_[e_ * 128 + c_ * 64 + lane];                           \
      _Pragma("unroll")                                                     \
      for (int t_ = 0; t_ < 2; ++t_)                                        \
        _Pragma("unroll")                                                   \
        for (int e_ = 0; e_ < 8; ++e_)                                      \
          sums[t_][e_] += xv[t_][c_].x * wr_[e_].x + xv[t_][c_].y * wr_[e_].y + \
                          xv[t_][c_].z * wr_[e_].z + xv[t_][c_].w * wr_[e_].w;  \
    }                                                                       \
    const int kb_ = (kc) * 128;                                             \
    _Pragma("unroll")                                                       \
    for (int t_ = 0; t_ < 2; ++t_) {                                        \
      ushort4* xo_ = (ushort4*)(xb + (size_t)(tok0 + t_) * DIM);            \
      _Pragma("unroll")                                                     \
      for (int c_ = 0; c_ < 2; ++c_) {                                      \
        float4 v_ = xv[t_][c_];                                             \
        ushort4 o_;                                                         \
        o_.x = f2bf(v_.x); o_.y = f2bf(v_.y);                               \
        o_.z = f2bf(v_.z); o_.w = f2bf(v_.w);                               \
        xo_[kb_ + c_ * 64 + lane] = o_;                                     \
      }                                                                     \
    }                                                                       \
  }

__global__ __launch_bounds__(256, 2) void router_kernel(
    const float* __restrict__ x, const float* __restrict__ Wr,
    const float* __restrict__ br, u16* __restrict__ xb,
    float* __restrict__ gw, int* __restrict__ sel) {
  __shared__ alignas(16) float WrL[2][4096];  // 2 x (8 experts x 512 f) = 32 KB

  const int tid = threadIdx.x;
  const int wv = tid >> 6, lane = tid & 63;
  const int tok0 = blockIdx.x * 8 + wv * 2;  // this wave's 2 tokens

  const float4* x4 = (const float4*)x;
  // Staging source: round r covers experts {2r, 2r+1}; thread t takes expert
  // 2r + (t>>7), floats (t&127)*4. Per wave the global src is contiguous and
  // the LDS dest is base + lane*16 (linear) — async16 constraint satisfied.
  const float* wsrc = Wr + (size_t)(tid >> 7) * DIM + (tid & 127) * 4;

  float4 xvA[2][2], xvB[2][2];
  float sums[2][8] = {};

  R_STAGE(0, 0); R_LOADX(0, xvA);
  for (int kc = 0; kc < 3; ++kc) {   // chunks 2kc, 2kc+1
    R_STAGE(2 * kc + 1, 1); R_LOADX(2 * kc + 1, xvB);
    PIPE_WAIT(8);
    R_COMPUTE(2 * kc, 0, xvA);
    PIPE_END();
    R_STAGE(2 * kc + 2, 0); R_LOADX(2 * kc + 2, xvA);
    PIPE_WAIT(8);
    R_COMPUTE(2 * kc + 1, 1, xvB);
    PIPE_END();
  }
  R_STAGE(7, 1); R_LOADX(7, xvB);
  PIPE_WAIT(8);
  R_COMPUTE(6, 0, xvA);
  PIPE_END();
  PIPE_WAIT(0);
  R_COMPUTE(7, 1, xvB);

  // Full-wave butterfly: every lane ends with complete sums for both tokens.
#pragma unroll
  for (int m = 1; m < 64; m <<= 1)
#pragma unroll
    for (int t = 0; t < 2; ++t)
#pragma unroll
      for (int e = 0; e < 8; ++e)
        sums[t][e] += __shfl_xor(sums[t][e], m, 64);

  if (lane < 2) {
    float fl[8];  // static-index select (rule #20: no runtime reg-array index)
#pragma unroll
    for (int e = 0; e < 8; ++e)
      fl[e] = (lane == 0) ? sums[0][e] : sums[1][e];
    router_finalize(tok0 + lane, fl, br, gw, sel);
  }
}

// ---------------------------------------------------------------- listbuild
// Ballot-aggregated expert-list compaction. 16 blocks x 512 thr, 1 token/thr.
__global__ __launch_bounds__(512) void listbuild_kernel(
    const int* __restrict__ sel, int* __restrict__ lists,
    int* __restrict__ cnt) {
  __shared__ int blkCnt[NEXP];
  __shared__ int gBase[NEXP];
  __shared__ int waveOff[8][NEXP];
  const int tid = threadIdx.x;
  const int wv = tid >> 6, lane = tid & 63;
  const int n = blockIdx.x * 512 + tid;
  if (tid < NEXP) blkCnt[tid] = 0;
  __syncthreads();
  const int s = sel[n];
  const int i0 = s & 15, i1 = (s >> 4) & 15;
#pragma unroll
  for (int e = 0; e < NEXP; ++e) {
    unsigned long long m0 = __ballot(i0 == e);
    unsigned long long m1 = __ballot(i1 == e);
    if (lane == 0)
      waveOff[wv][e] = atomicAdd(&blkCnt[e], __popcll(m0) + __popcll(m1));
  }
  __syncthreads();
  if (tid < NEXP) gBase[tid] = atomicAdd(&cnt[tid], blkCnt[tid]);
  __syncthreads();
  const unsigned long long lt = (1ull << lane) - 1;
#pragma unroll
  for (int e = 0; e < NEXP; ++e) {
    unsigned long long m0 = __ballot(i0 == e);
    unsigned long long m1 = __ballot(i1 == e);
    int base = gBase[e] + waveOff[wv][e];
    if (i0 == e) lists[e * N_TOK + base + (int)__popcll(m0 & lt)] = n * 2;
    if (i1 == e)
      lists[e * N_TOK + base + (int)__popcll(m0) + (int)__popcll(m1 & lt)] =
          n * 2 + 1;
  }
}

// ---------------------------------------------------------------- GEMM1
// Per expert: h[entry, r] = xb[token] . Ab[e][r], scaled by gate*SCAL -> G bf16.
// R4 post-mortem: ring-4/BK=32 landed at 94us = 1763 cy/iter with ~40cy MFMA —
// NOT latency (depth-3 gives loads >5000cy) but GATHER BANDWIDTH: staging
// fetched 64B segments from 64 random 8KB-strided token rows; xb (67MB) never
// L2-hits, so A-traffic (134MB) at random-64B L3 rate (~1.4TB/s) = ~95us ==
// measured. FETCH 84MB ~= xb+Ab full re-read corroborates.
// R5: BK=64 staging -> 128B FULL-LINE segments (8 lanes/row). 128B LDS rows
// would be a 16-way read conflict, so the T2 involution (rule #21): stage
// from XOR-pre-swizzled global column cgs = cg ^ (row&7) into LINEAR LDS;
// read 16B-unit c = u ^ (row&7). Residual ~8 lanes/bank-group (pigeonhole of
// 128B rows) ~= 3x on ds_read — acceptable vs the gather saving.
// Ring-4 slots (A 8KB + B 16KB = 96KB), 6 loads/wave/stage, vmcnt(12), 64 it.
__global__ __launch_bounds__(256) void gemm1_kernel(
    const u16* __restrict__ xb, const u16* __restrict__ Ab,
    const int* __restrict__ lists, const int* __restrict__ cnt,
    const float* __restrict__ gw, u16* __restrict__ G) {
  const int e = blockIdx.y;
  const int mt = blockIdx.x;
  const int c = cnt[e];
  if (mt * 64 >= c) return;

  __shared__ alignas(16) u16 ringA[4][64 * 64];    //  8 KB per slot (BK=64)
  __shared__ alignas(16) u16 ringB[4][128 * 64];   // 16 KB per slot
  __shared__ int   tokS[64];
  __shared__ float wS[64];

  const int tid = threadIdx.x;
  if (tid < 64) {
    int idx = mt * 64 + tid;
    int ci = idx < c ? idx : (c - 1);
    int entry = lists[e * N_TOK + ci];
    tokS[tid] = entry >> 1;
    wS[tid] = (idx < c) ? gw[entry] : 0.0f;
  }
  __syncthreads();

  const int srow = tid >> 3;                 // staging row 0..31 (+32k per instr)
  const int cg   = tid & 7;                  // 16B unit within 128B row
  const int cgs  = cg ^ (srow & 7);          // XOR-pre-swizzled source unit;
                                             // row+32/64/96 keep (row&7) -> one cgs
  const u16* gA0 = xb + (size_t)tokS[srow] * DIM + cgs * 8;
  const u16* gA1 = xb + (size_t)tokS[srow + 32] * DIM + cgs * 8;
  const u16* gB0 = Ab + (size_t)e * (RANK * DIM) + (size_t)srow * DIM + cgs * 8;

  const int lane = tid & 63, wvi = tid >> 6;
  const int wm = wvi >> 1, wn = wvi & 1;
  const int m16 = lane & 15, quad = lane >> 4;
  const int swz = m16 & 7;                   // read-side XOR (row&7 == m16&7)

  f32x4 acc[2][4] = {};

  auto STAGE = [&](int kt, int slot) {
    const int k0 = kt * 64;
    // 6 loads per wave, uniform across waves (vmcnt correctness).
    async16(&ringA[slot][tid * 8],        gA0 + k0);   // A rows  0..31
    async16(&ringA[slot][tid * 8 + 2048], gA1 + k0);   // A rows 32..63
#pragma unroll
    for (int r = 0; r < 4; ++r)                        // B rows r*32..r*32+31
      async16(&ringB[slot][tid * 8 + r * 2048], gB0 + (size_t)r * 32 * DIM + k0);
  };

  auto COMPUTE = [&](int slot) {
#pragma unroll
    for (int ks = 0; ks < 2; ++ks) {
      const int off = ((ks * 4 + quad) ^ swz) * 8;  // swizzled 16B unit -> elems
      bf16x8 af[2], bfr[4];
#pragma unroll
      for (int j = 0; j < 4; ++j)
        bfr[j] = *(const bf16x8*)&ringB[slot][(wn * 64 + j * 16 + m16) * 64 + off];
#pragma unroll
      for (int i = 0; i < 2; ++i)
        af[i] = *(const bf16x8*)&ringA[slot][(wm * 32 + i * 16 + m16) * 64 + off];
      __builtin_amdgcn_s_setprio(1);  // T5: favor the MFMA cluster
#pragma unroll
      for (int i = 0; i < 2; ++i)
#pragma unroll
        for (int j = 0; j < 4; ++j) acc[i][j] = mfma16(af[i], bfr[j], acc[i][j]);
      __builtin_amdgcn_s_setprio(0);
    }
  };

  // Prologue: fill 3 of 4 ring slots (18 loads/wave in flight).
  STAGE(0, 0);
  STAGE(1, 1);
  STAGE(2, 2);

  // Main loop: 64 K-tiles (DIM/64). vmcnt(12) = tiles t+1,t+2 stay in flight.
  for (int t = 0; t < 61; ++t) {
    PIPE_WAIT(12);
    STAGE(t + 3, (t + 3) & 3);  // overlapped with compute below
    COMPUTE(t & 3);
    PIPE_END();
  }
  PIPE_WAIT(12); COMPUTE(1); PIPE_END();  // t=61
  PIPE_WAIT(6);  COMPUTE(2); PIPE_END();  // t=62
  PIPE_WAIT(0);  COMPUTE(3); PIPE_END();  // t=63

#pragma unroll
  for (int i = 0; i < 2; ++i)
#pragma unroll
    for (int rr = 0; rr < 4; ++rr) {
      int row = wm * 32 + i * 16 + quad * 4 + rr;  // C/D: row=quad*4+reg
      if (mt * 64 + row < c) {
        int tk = tokS[row];
        float wgt = wS[row];
        u16* gp = G + (size_t)tk * EK + e * RANK + wn * 64 + m16;  // col=lane&15
#pragma unroll
        for (int j = 0; j < 4; ++j) gp[j * 16] = f2bf(acc[i][j][rr] * wgt);
      }
    }
}

// ---------------------------------------------------------------- GEMM2
// Dense: out[8192,4096] = G[8192,1024] @ Bt[4096,1024]^T.
// 256x256 tile, BK=32, 512 thr (8 waves 2x4, each 128x64 of C).
// 4-slot LDS ring (128 KiB), prefetch depth 3, counted s_waitcnt vmcnt(8) —
// loads NEVER drain to 0 in the main loop (T3+T4). Raw s_barrier only.
// LAUNCH MUST BE dim3(16,32) x 512 — R3's crash was a stale dim3(32,64)x256
// launch of this kernel (half-staged tile + swizzle OOB on out rows).
__global__ __launch_bounds__(512, 2) void gemm2_kernel(
    const u16* __restrict__ G, const u16* __restrict__ Bt,
    float* __restrict__ out) {
  __shared__ alignas(16) u16 ring[4][2][256 * 32];  // 4 x (A 16KB + B 16KB)

  // T1: bijective XCD swizzle (512 wgs, 512 % 8 == 0). XCD x gets a
  // contiguous band of 4 m-tiles (1024 G rows = 2 MB, L2-resident).
  const int lin = blockIdx.y * 16 + blockIdx.x;
  const int swz = (lin & 7) * 64 + (lin >> 3);
  const int by = swz >> 4;  // m-tile 0..31
  const int bx = swz & 15;  // n-tile 0..15

  const int tid = threadIdx.x;
  const int sr = tid >> 2;        // staging row 0..127 within half
  const int sc = (tid & 3) * 8;   // staging 16B col group
  const u16* gA = G  + (size_t)(by * 256 + sr) * EK + sc;
  const u16* gB = Bt + (size_t)(bx * 256 + sr) * EK + sc;

  const int lane = tid & 63, wvi = tid >> 6;  // 8 waves
  const int wm = wvi >> 2, wn = wvi & 3;      // 2 x 4 wave grid
  const int m16 = lane & 15, quad = lane >> 4;

  f32x4 acc[8][4] = {};

  auto STAGE = [&](int kt, int slot) {
    u16* lA = &ring[slot][0][tid * 8];   // linear dest = base + tid*16B
    u16* lB = &ring[slot][1][tid * 8];
    const u16* sA = gA + kt * 32;
    const u16* sB = gB + kt * 32;
    async16(lA,        sA);
    async16(lA + 4096, sA + (size_t)128 * EK);
    async16(lB,        sB);
    async16(lB + 4096, sB + (size_t)128 * EK);
  };

  auto COMPUTE = [&](int slot) {
    const u16* As_ = &ring[slot][0][0];
    const u16* Bs_ = &ring[slot][1][0];
    bf16x8 bfr[4];
#pragma unroll
    for (int j = 0; j < 4; ++j)
      bfr[j] = *(const bf16x8*)&Bs_[(wn * 64 + j * 16 + m16) * 32 + quad * 8];
    __builtin_amdgcn_s_setprio(1);  // T5: favor the MFMA cluster
#pragma unroll
    for (int i = 0; i < 8; ++i) {
      bf16x8 af = *(const bf16x8*)&As_[(wm * 128 + i * 16 + m16) * 32 + quad * 8];
#pragma unroll
      for (int j = 0; j < 4; ++j) acc[i][j] = mfma16(af, bfr[j], acc[i][j]);
    }
    __builtin_amdgcn_s_setprio(0);
  };

  // Prologue: fill 3 of 4 ring slots (12 loads in flight).
  STAGE(0, 0);
  STAGE(1, 1);
  STAGE(2, 2);

  // Main loop: 32 K-tiles (EK/32). vmcnt(8) = tiles t+1,t+2 stay in flight.
  for (int t = 0; t < 29; ++t) {
    PIPE_WAIT(8);
    STAGE(t + 3, (t + 3) & 3);  // overlapped with compute below
    COMPUTE(t & 3);
    PIPE_END();
  }
  PIPE_WAIT(8); COMPUTE(1); PIPE_END();  // t=29
  PIPE_WAIT(4); COMPUTE(2); PIPE_END();  // t=30
  PIPE_WAIT(0); COMPUTE(3); PIPE_END();  // t=31

#pragma unroll
  for (int i = 0; i < 8; ++i)
#pragma unroll
    for (int rr = 0; rr < 4; ++rr) {
      int row = by * 256 + wm * 128 + i * 16 + quad * 4 + rr;
      float* op = out + (size_t)row * DIM + bx * 256 + wn * 64 + m16;
#pragma unroll
      for (int j = 0; j < 4; ++j) op[j * 16] = acc[i][j][rr];
    }
}

// ---------------------------------------------------------------- launch
extern "C" void kernel_launch(void* const* d_in, const int* in_sizes, int n_in,
                              void* d_out, int out_size, void* d_ws, size_t ws_size,
                              hipStream_t stream) {
  const float* x  = (const float*)d_in[0];
  const float* Wr = (const float*)d_in[1];
  const float* br = (const float*)d_in[2];
  const float* A  = (const float*)d_in[3];
  const float* B  = (const float*)d_in[4];
  float* out = (float*)d_out;

  char* w = (char*)d_ws;
  u16* xb = (u16*)w;      w += (size_t)N_TOK * DIM * 2;        // 67.1 MB
  u16* G  = (u16*)w;      w += (size_t)N_TOK * EK * 2;         // 16.8 MB
  u16* Ab = (u16*)w;      w += (size_t)NEXP * RANK * DIM * 2;  //  8.4 MB
  u16* Bt = (u16*)w;      w += (size_t)DIM * EK * 2;           //  8.4 MB
  float* gw = (float*)w;  w += (size_t)N_TOK * 2 * 4;          // 64 KB
  int* lists = (int*)w;   w += (size_t)NEXP * N_TOK * 4;       // 256 KB
  int* sel = (int*)w;     w += (size_t)N_TOK * 4;              // 32 KB
  int* cnt = (int*)w;     w += 256;

  hipMemsetAsync(cnt, 0, NEXP * sizeof(int), stream);
  hipMemsetAsync(G, 0, (size_t)N_TOK * EK * 2, stream);  // unselected blocks = 0

  cvtA_kernel<<<dim3(4096), dim3(256), 0, stream>>>(A, Ab);
  cvtB_kernel<<<dim3(4096), dim3(256), 0, stream>>>(B, Bt);
  router_kernel<<<dim3(1024), dim3(256), 0, stream>>>(x, Wr, br, xb, gw, sel);
  listbuild_kernel<<<dim3(16), dim3(512), 0, stream>>>(sel, lists, cnt);
  gemm1_kernel<<<dim3(128, NEXP), dim3(256), 0, stream>>>(xb, Ab, lists, cnt, gw, G);
  gemm2_kernel<<<dim3(16, 32), dim3(512), 0, stream>>>(G, Bt, out);
}